// Round 13
// baseline (16215.523 us; speedup 1.0000x reference)
//
#include <hip/hip_runtime.h>
#include <hip/hip_fp16.h>
#include <stdint.h>

#define Kn 64
#define En 256
#define Bn 512
#define Hn 512
#define Dn 128
#define NBLK 32      // 32 independent blocks x 16 samples, zero inter-block sync
#define NTH  512     // 8 waves
#define DT_C 0.05f

// ws layout (bytes):
//   0        pos  int[Kn*Bn]   (128 KB)
//   131072   acc  float[2]
//   4194304  WF   frag-swizzled f16 weights (4.33 MB)
// WF half-offsets: W1 0, W2 262144, Wp1 524288, Wp2 786432, Wg 851968
//   std frag (KT,N): idx=((ct*KT+kt)*64+l)*8+e ; elem=W[kt*32+(l>>4)*8+e][ct*16+(l&15)]
//   Wg interleaved: ct = hcoltile*4 + gate (KT=20, rows 0..127 = X part)

typedef _Float16 f16x8 __attribute__((ext_vector_type(8)));
typedef float    f32x4 __attribute__((ext_vector_type(4)));
typedef unsigned long long u64;

__device__ __forceinline__ float sigm(float x){ return 1.0f/(1.0f + __expf(-x)); }

__global__ void k_init(int* __restrict__ pos, float* __restrict__ acc){
  int i = blockIdx.x*blockDim.x + threadIdx.x;
  if (i < Kn*Bn) pos[i] = -1;
  if (i < 2) acc[i] = 0.0f;
}

__global__ void k_scatter(const int* __restrict__ bidx, int* __restrict__ pos){
  int i = blockIdx.x*blockDim.x + threadIdx.x;
  if (i < Kn*En){
    int k = i >> 8;
    int e = i & (En-1);
    pos[(k << 9) | bidx[i]] = e;
  }
}

__global__ void k_cvt_frag(const float* __restrict__ src, __half* __restrict__ dst,
                           int KT, int N, int n){
  int i = blockIdx.x*blockDim.x + threadIdx.x;
  if (i >= n) return;
  int C = i / (KT*512);
  int r = i % (KT*512);
  int T = r >> 9;
  int q = r & 511;
  int l = q >> 3, e = q & 7;
  int srow = T*32 + ((l>>4)<<3) + e;
  int scol = C*16 + (l&15);
  dst[i] = __float2half(src[(size_t)srow*N + scol]);
}

// gate matrices interleaved by h-coltile: dst ct = C*4 + gate
__global__ void k_cvt_gate(const float* __restrict__ src, __half* __restrict__ dst,
                           int gate){
  int i = blockIdx.x*blockDim.x + threadIdx.x;
  if (i >= 32*20*512) return;
  int C = i / (20*512);
  int r = i % (20*512);
  int T = r >> 9;
  int q = r & 511;
  int l = q >> 3, e = q & 7;
  int srow = T*32 + ((l>>4)<<3) + e;
  int scol = C*16 + (l&15);
  dst[((((size_t)C*4 + gate)*20 + T)*64 + l)*8 + e] =
      __float2half(src[(size_t)srow*512 + scol]);
}

__global__ __launch_bounds__(NTH, 1) void k_main(
  const float* __restrict__ X, const float* __restrict__ Mm,
  const int* __restrict__ pos, const __half* __restrict__ WF,
  const float* __restrict__ bi_, const float* __restrict__ bf_,
  const float* __restrict__ bo_, const float* __restrict__ bc_,
  const float* __restrict__ b1_, const float* __restrict__ b2_,
  const float* __restrict__ bp1_, const float* __restrict__ bp2_,
  float* __restrict__ acc)
{
  const __half* W1F  = WF;
  const __half* W2F  = WF + 262144;
  const __half* Wp1F = WF + 524288;
  const __half* Wp2F = WF + 786432;
  const __half* WgF  = WF + 851968;

  const int t    = threadIdx.x;
  const int g    = blockIdx.x;        // sample rows g*16 .. g*16+15
  const int w    = t >> 6;            // wave 0..7
  const int lane = t & 63;
  const int li   = lane & 15;         // col within 16-tile
  const int lq   = lane >> 4;         // row quad

  __shared__ __align__(16) __half Afrag[8192];  // 16KB: h state, frag layout
  __shared__ __align__(16) __half Tfrag[8192];  // 16KB: tanh/relu intermediate
  __shared__ __align__(16) __half Xfrag[2048];  // 4KB
  __shared__ int   posk[16];
  __shared__ float redbuf[16];

  // per-lane bias scalars (cols (w*4+j)*16+li)
  float b1v[4], b2v[4], bp1v[4], biv[4], bfv[4], bov[4], bcv[4];
  int   sbase[4];
  #pragma unroll
  for (int j=0;j<4;j++){
    const int col = (w*4+j)*16 + li;
    b1v[j]=b1_[col]; b2v[j]=b2_[col]; bp1v[j]=bp1_[col];
    biv[j]=bi_[col]; bfv[j]=bf_[col]; bov[j]=bo_[col]; bcv[j]=bc_[col];
    sbase[j] = (col>>5)*512 + (((col&31)>>3)<<4)*8 + (col&7);  // frag scatter base
  }
  const float bp2v = bp2_[w*16 + li];

  float Hreg[16], Creg[16];
  #pragma unroll
  for (int i=0;i<16;i++){ Hreg[i]=0.f; Creg[i]=0.f; }

  for (int i=t;i<2048;i+=NTH) ((u64*)Afrag)[i] = 0;   // h=0
  __syncthreads();

  float loss_loc=0.f, m_loc=0.f;

// matvec over 512x512 frag matrix: 4 coltiles/wave, A from LDS (1 read/kt)
#define MV4(AF, WBASE, ACC) do{                                          \
    const __half* _wb = (WBASE) + (size_t)(w*4)*16*512 + (size_t)lane*8; \
    _Pragma("unroll")                                                    \
    for (int kt=0; kt<16; kt++){                                         \
      f16x8 a = *(const f16x8*)((AF) + kt*512 + lane*8);                 \
      _Pragma("unroll")                                                  \
      for (int j=0;j<4;j++){                                             \
        f16x8 b = *(const f16x8*)(_wb + (size_t)(j*16 + kt)*512);        \
        ACC[j] = __builtin_amdgcn_mfma_f32_16x16x32_f16(a, b, ACC[j], 0,0,0); \
      }                                                                  \
    }                                                                    \
  }while(0)

  for (int k=0; k<Kn; k++){
    // ---- Euler step 1: tanh(h@W1+b1) -> Tfrag ----
    {
      f32x4 a1[4];
      #pragma unroll
      for (int j=0;j<4;j++) a1[j]=(f32x4){0,0,0,0};
      MV4(Afrag, W1F, a1);
      #pragma unroll
      for (int j=0;j<4;j++)
        #pragma unroll
        for (int i=0;i<4;i++)
          Tfrag[sbase[j] + (lq*4+i)*8] = __float2half(tanhf(a1[j][i] + b1v[j]));
    }
    __syncthreads();
    // ---- Euler step 1: h += dt*(T@W2+b2) (in-lane), write Afrag ----
    {
      f32x4 a2[4];
      #pragma unroll
      for (int j=0;j<4;j++) a2[j]=(f32x4){0,0,0,0};
      MV4(Tfrag, W2F, a2);
      #pragma unroll
      for (int j=0;j<4;j++)
        #pragma unroll
        for (int i=0;i<4;i++){
          Hreg[j*4+i] += DT_C*(a2[j][i] + b2v[j]);
          Afrag[sbase[j] + (lq*4+i)*8] = __float2half(Hreg[j*4+i]);
        }
    }
    __syncthreads();
    // ---- Euler step 2 (same two phases); Xfrag+posk staged in parallel ----
    if (t < 16) posk[t] = pos[(k<<9) + g*16 + t];
    if (t < 64){
      const int ar = t & 15, ch = t >> 4;
      const int e = pos[(k<<9) + g*16 + ar];
      float xv[32];
      if (e >= 0){
        const float4* xp = (const float4*)(X + ((size_t)(k*En+e))*Dn + ch*32);
        #pragma unroll
        for (int i=0;i<8;i++){
          float4 f = xp[i];
          xv[4*i]=f.x; xv[4*i+1]=f.y; xv[4*i+2]=f.z; xv[4*i+3]=f.w;
        }
      } else {
        #pragma unroll
        for (int i=0;i<32;i++) xv[i]=0.f;
      }
      #pragma unroll
      for (int kg=0;kg<4;kg++){
        union { __half h[8]; u64 q[2]; } u;
        #pragma unroll
        for (int e8=0;e8<8;e8++) u.h[e8] = __float2half(xv[kg*8+e8]);
        u64* d = (u64*)(Xfrag + ch*512 + (ar + 16*kg)*8);
        d[0] = u.q[0]; d[1] = u.q[1];
      }
    }
    {
      f32x4 a1[4];
      #pragma unroll
      for (int j=0;j<4;j++) a1[j]=(f32x4){0,0,0,0};
      MV4(Afrag, W1F, a1);
      #pragma unroll
      for (int j=0;j<4;j++)
        #pragma unroll
        for (int i=0;i<4;i++)
          Tfrag[sbase[j] + (lq*4+i)*8] = __float2half(tanhf(a1[j][i] + b1v[j]));
    }
    __syncthreads();
    {
      f32x4 a2[4];
      #pragma unroll
      for (int j=0;j<4;j++) a2[j]=(f32x4){0,0,0,0};
      MV4(Tfrag, W2F, a2);
      #pragma unroll
      for (int j=0;j<4;j++)
        #pragma unroll
        for (int i=0;i<4;i++){
          Hreg[j*4+i] += DT_C*(a2[j][i] + b2v[j]);
          Afrag[sbase[j] + (lq*4+i)*8] = __float2half(Hreg[j*4+i]);
        }
    }
    __syncthreads();

    // ---- Wp1 -> relu -> Tfrag ; gates (in-lane accumulators) ----
    f32x4 gacc[16];
    {
      f32x4 p1[4];
      #pragma unroll
      for (int j=0;j<4;j++) p1[j]=(f32x4){0,0,0,0};
      MV4(Afrag, Wp1F, p1);
      #pragma unroll
      for (int j=0;j<4;j++)
        #pragma unroll
        for (int i=0;i<4;i++)
          Tfrag[sbase[j] + (lq*4+i)*8] = __float2half(fmaxf(p1[j][i] + bp1v[j], 0.f));
    }
    if (k < Kn-1){
      // two passes of 2 hcol-tiles x 4 gates (8 accs) to bound register pressure
      #pragma unroll
      for (int p=0;p<2;p++){
        f32x4 ga[8];
        #pragma unroll
        for (int i=0;i<8;i++) ga[i]=(f32x4){0,0,0,0};
        const __half* wgb = WgF + (size_t)((w*4 + p*2)*4)*20*512 + (size_t)lane*8;
        #pragma unroll
        for (int kt=0; kt<4; kt++){
          f16x8 a = *(const f16x8*)(Xfrag + kt*512 + lane*8);
          #pragma unroll
          for (int jj=0;jj<2;jj++)
            #pragma unroll
            for (int gg2=0;gg2<4;gg2++){
              f16x8 b = *(const f16x8*)(wgb + (size_t)((jj*4+gg2)*20 + kt)*512);
              ga[jj*4+gg2] = __builtin_amdgcn_mfma_f32_16x16x32_f16(a, b, ga[jj*4+gg2], 0,0,0);
            }
        }
        #pragma unroll
        for (int kt=4; kt<20; kt++){
          f16x8 a = *(const f16x8*)(Afrag + (kt-4)*512 + lane*8);
          #pragma unroll
          for (int jj=0;jj<2;jj++)
            #pragma unroll
            for (int gg2=0;gg2<4;gg2++){
              f16x8 b = *(const f16x8*)(wgb + (size_t)((jj*4+gg2)*20 + kt)*512);
              ga[jj*4+gg2] = __builtin_amdgcn_mfma_f32_16x16x32_f16(a, b, ga[jj*4+gg2], 0,0,0);
            }
        }
        #pragma unroll
        for (int i=0;i<8;i++) gacc[p*8+i] = ga[i];
      }
    }
    __syncthreads();

    // ---- Wp2 (1 coltile/wave) -> loss ; LSTM update (in-lane) ----
    {
      f32x4 p2 = {0,0,0,0};
      const __half* wb = Wp2F + (size_t)(w*16)*512 + (size_t)lane*8;
      #pragma unroll
      for (int kt=0; kt<16; kt++){
        f16x8 a = *(const f16x8*)(Tfrag + kt*512 + lane*8);
        f16x8 b = *(const f16x8*)(wb + (size_t)kt*512);
        p2 = __builtin_amdgcn_mfma_f32_16x16x32_f16(a, b, p2, 0,0,0);
      }
      #pragma unroll
      for (int i=0;i<4;i++){
        const int r  = lq*4 + i;
        const int ep = posk[r];
        if (ep >= 0){
          const size_t xo = ((size_t)(k*En+ep))*Dn + w*16 + li;
          float mo = Mm[xo];
          loss_loc += fabsf(X[xo] - (p2[i] + bp2v)) * mo;
          m_loc    += mo;
        }
      }
    }
    if (k < Kn-1){
      #pragma unroll
      for (int j=0;j<4;j++){
        // gacc index: j = (pass p)*2 + jj, gates at [j*4 + gate]... mapping:
        // pass p covers tiles w*4+p*2 + jj -> j_global = p*2+jj; gacc[p*8 + jj*4 + gg]
        #pragma unroll
        for (int i=0;i<4;i++){
          const int r = lq*4 + i;
          if (posk[r] >= 0){
            const int p  = j >> 1, jj = j & 1;
            float ig = sigm (gacc[p*8 + jj*4 + 0][i] + biv[j]);
            float fg = sigm (gacc[p*8 + jj*4 + 1][i] + bfv[j]);
            float og = sigm (gacc[p*8 + jj*4 + 2][i] + bov[j]);
            float ct = tanhf(gacc[p*8 + jj*4 + 3][i] + bcv[j]);
            Creg[j*4+i] = fg*Creg[j*4+i] + ig*ct;
            Hreg[j*4+i] = og*tanhf(Creg[j*4+i]);
            Afrag[sbase[j] + r*8] = __float2half(Hreg[j*4+i]);
          }
        }
      }
    }
    __syncthreads();
  }

  // block reduction -> global atomics
  #pragma unroll
  for (int off=32; off>0; off>>=1){
    loss_loc += __shfl_down(loss_loc, off);
    m_loc    += __shfl_down(m_loc, off);
  }
  if (lane == 0){ redbuf[w] = loss_loc; redbuf[8+w] = m_loc; }
  __syncthreads();
  if (t == 0){
    float L=0.f, Mt=0.f;
    #pragma unroll
    for (int i=0;i<8;i++){ L += redbuf[i]; Mt += redbuf[8+i]; }
    atomicAdd(acc+0, L);
    atomicAdd(acc+1, Mt);
  }
#undef MV4
}

__global__ void k_fin(const float* __restrict__ acc, float* __restrict__ out){
  if (threadIdx.x == 0){
    out[0] = acc[0];
    out[1] = acc[0]/acc[1];
  }
}

extern "C" void kernel_launch(void* const* d_in, const int* in_sizes, int n_in,
                              void* d_out, int out_size, void* d_ws, size_t ws_size,
                              hipStream_t stream)
{
  const float* X   = (const float*)d_in[0];
  const float* Mm  = (const float*)d_in[1];
  const int*  bidx = (const int*)d_in[2];
  // d_in[3] = sample_idx (arange, unused)
  const float* Wi  = (const float*)d_in[4];
  const float* bi  = (const float*)d_in[5];
  const float* Wf  = (const float*)d_in[6];
  const float* bff = (const float*)d_in[7];
  const float* Wo  = (const float*)d_in[8];
  const float* bo  = (const float*)d_in[9];
  const float* Wc  = (const float*)d_in[10];
  const float* bc  = (const float*)d_in[11];
  const float* W1  = (const float*)d_in[12];
  const float* b1  = (const float*)d_in[13];
  const float* W2  = (const float*)d_in[14];
  const float* b2  = (const float*)d_in[15];
  const float* Wp1 = (const float*)d_in[16];
  const float* bp1 = (const float*)d_in[17];
  const float* Wp2 = (const float*)d_in[18];
  const float* bp2 = (const float*)d_in[19];

  char* ws = (char*)d_ws;
  int*    pos = (int*)ws;
  float*  acc = (float*)(ws + 131072);
  __half* WF  = (__half*)(ws + 4194304);

  k_init   <<<(Kn*Bn + 255)/256, 256, 0, stream>>>(pos, acc);
  k_scatter<<<(Kn*En + 255)/256, 256, 0, stream>>>(bidx, pos);

  k_cvt_frag<<<(262144+255)/256, 256, 0, stream>>>(W1,  WF,          16, 512, 262144);
  k_cvt_frag<<<(262144+255)/256, 256, 0, stream>>>(W2,  WF + 262144, 16, 512, 262144);
  k_cvt_frag<<<(262144+255)/256, 256, 0, stream>>>(Wp1, WF + 524288, 16, 512, 262144);
  k_cvt_frag<<<(65536 +255)/256, 256, 0, stream>>>(Wp2, WF + 786432, 16, 128, 65536);
  k_cvt_gate<<<(327680+255)/256, 256, 0, stream>>>(Wi, WF + 851968, 0);
  k_cvt_gate<<<(327680+255)/256, 256, 0, stream>>>(Wf, WF + 851968, 1);
  k_cvt_gate<<<(327680+255)/256, 256, 0, stream>>>(Wo, WF + 851968, 2);
  k_cvt_gate<<<(327680+255)/256, 256, 0, stream>>>(Wc, WF + 851968, 3);

  k_main<<<NBLK, NTH, 0, stream>>>(X, Mm, pos, WF,
                                   bi, bff, bo, bc, b1, b2, bp1, bp2, acc);
  k_fin<<<1, 64, 0, stream>>>(acc, (float*)d_out);
}

// Round 14
// 3371.012 us; speedup vs baseline: 4.8103x; 4.8103x over previous
//
#include <hip/hip_runtime.h>
#include <hip/hip_fp16.h>
#include <stdint.h>

#define Kn 64
#define En 256
#define Bn 512
#define Hn 512
#define Dn 128
#define NBLK 128     // 32 groups x 4 slice-blocks (128 cols each)
#define NTH  512     // 8 waves
#define DT_C 0.05f

// ws layout (bytes):
//   0        pos   int[Kn*Bn]           (128 KB)
//   131072   acc   float[2]
//   196608   flg   int[32*4*32]         (16 KB: [group][slice], 128B stride)
//   1048576  Hf    __half[512][512]     Euler h mirror
//   1572864  Tf    __half[512][512]     Euler tanh mirror
//   2097152  T2f   __half[512][512]     P1 relu mirror (deferred P2)
//   2621440  Hf2   __half[512][512]     LSTM h' mirror (obs rows)
//   4194304  WF    frag-swizzled f16 weights (4.33 MB)
// WF half-offsets: W1 0, W2 262144, Wp1 524288, Wp2 786432, Wg 851968
//   std frag: idx=((ct*KT+kt)*64+l)*8+e ; elem=W[kt*32+(l>>4)*8+e][ct*16+(l&15)]
//   Wg interleaved: ct = hcoltile*4 + gate (KT=20; rows 0..127 = X part)

typedef _Float16 f16x8 __attribute__((ext_vector_type(8)));
typedef float    f32x4 __attribute__((ext_vector_type(4)));
typedef unsigned long long u64;

__device__ __forceinline__ float sigm(float x){ return 1.0f/(1.0f + __expf(-x)); }

__device__ __forceinline__ u64 ald(const u64* p){
  return __hip_atomic_load(p, __ATOMIC_RELAXED, __HIP_MEMORY_SCOPE_AGENT);
}
__device__ __forceinline__ void ash(__half* p, float v){
  __hip_atomic_store((unsigned short*)p, __half_as_ushort(__float2half(v)),
                     __ATOMIC_RELAXED, __HIP_MEMORY_SCOPE_AGENT);
}

__global__ void k_init(int* __restrict__ pos, float* __restrict__ acc,
                       int* __restrict__ flg, uint32_t* __restrict__ hf){
  int i = blockIdx.x*blockDim.x + threadIdx.x;
  if (i < Kn*Bn) pos[i] = -1;
  if (i < 2) acc[i] = 0.0f;
  if (i < 32*4*32) flg[i] = 0;
  if (i < Hn*Hn/2) hf[i] = 0;
}

__global__ void k_scatter(const int* __restrict__ bidx, int* __restrict__ pos){
  int i = blockIdx.x*blockDim.x + threadIdx.x;
  if (i < Kn*En){
    int k = i >> 8;
    int e = i & (En-1);
    pos[(k << 9) | bidx[i]] = e;
  }
}

__global__ void k_cvt_frag(const float* __restrict__ src, __half* __restrict__ dst,
                           int KT, int N, int n){
  int i = blockIdx.x*blockDim.x + threadIdx.x;
  if (i >= n) return;
  int C = i / (KT*512);
  int r = i % (KT*512);
  int T = r >> 9;
  int q = r & 511;
  int l = q >> 3, e = q & 7;
  int srow = T*32 + ((l>>4)<<3) + e;
  int scol = C*16 + (l&15);
  dst[i] = __float2half(src[(size_t)srow*N + scol]);
}

// gate matrices interleaved by h-coltile: dst ct = C*4 + gate
__global__ void k_cvt_gate(const float* __restrict__ src, __half* __restrict__ dst,
                           int gate){
  int i = blockIdx.x*blockDim.x + threadIdx.x;
  if (i >= 32*20*512) return;
  int C = i / (20*512);
  int r = i % (20*512);
  int T = r >> 9;
  int q = r & 511;
  int l = q >> 3, e = q & 7;
  int srow = T*32 + ((l>>4)<<3) + e;
  int scol = C*16 + (l&15);
  dst[((((size_t)C*4 + gate)*20 + T)*64 + l)*8 + e] =
      __float2half(src[(size_t)srow*512 + scol]);
}

__device__ __forceinline__ f32x4 mv16r(const __half* Af, const f16x8* Wr, int lane){
  f32x4 a = {0.f,0.f,0.f,0.f};
  #pragma unroll
  for (int kt=0; kt<16; kt++){
    f16x8 av = *(const f16x8*)(Af + kt*512 + lane*8);
    a = __builtin_amdgcn_mfma_f32_16x16x32_f16(av, Wr[kt], a, 0,0,0);
  }
  return a;
}

__global__ __launch_bounds__(NTH, 1) void k_main(
  const float* __restrict__ X, const float* __restrict__ Mm,
  const int* __restrict__ pos, const __half* __restrict__ WF,
  __half* __restrict__ Hf, __half* __restrict__ Tf,
  __half* __restrict__ T2f, __half* __restrict__ Hf2,
  const float* __restrict__ bi_, const float* __restrict__ bf_,
  const float* __restrict__ bo_, const float* __restrict__ bc_,
  const float* __restrict__ b1_, const float* __restrict__ b2_,
  const float* __restrict__ bp1_, const float* __restrict__ bp2_,
  float* __restrict__ acc, int* __restrict__ flg)
{
  const __half* W1F  = WF;
  const __half* W2F  = WF + 262144;
  const __half* Wp1F = WF + 524288;
  const __half* Wp2F = WF + 786432;
  const __half* WgF  = WF + 851968;

  const int t    = threadIdx.x;
  const int bid  = blockIdx.x;
  const int s    = bid & 3;      // slice 0..3 (128 cols)
  const int g    = bid >> 2;     // group 0..31
  const int w    = t >> 6;       // wave 0..7
  const int lane = t & 63;
  const int li   = lane & 15;
  const int lq   = lane >> 4;
  int* flgbase = flg + g*4*32;

  __shared__ __align__(16) __half Afrag[8192];   // 16KB
  __shared__ __align__(16) __half Bfrag[8192];   // 16KB (T2f staging)
  __shared__ __align__(16) __half Xfrag[2048];   // 4KB
  __shared__ __align__(16) float  outb[2048];    // 8KB (deferred P2 partials)
  __shared__ int   posk[16];
  __shared__ float redbuf[16];

  const int ctw  = s*8 + w;              // owned h-coltile
  const int colg = ctw*16 + li;          // owned h-col
  const float b1v=b1_[colg], b2v=b2_[colg], bp1v=bp1_[colg];
  const float biv=bi_[colg], bfv=bf_[colg], bov=bo_[colg], bcv=bc_[colg];
  const float bp2v = bp2_[s*32 + (t&31)];

  float Hreg[4]={0,0,0,0}, Creg[4]={0,0,0,0};   // rows lq*4+i, col colg

  // hoist W1/W2 (critical Euler path); Wp1/Wp2/Wg streamed (L2-warm)
  f16x8 W1r[16], W2r[16];
  {
    const size_t cb = (size_t)ctw*16*512 + (size_t)lane*8;
    #pragma unroll
    for (int kt=0; kt<16; kt++){
      W1r[kt] = *(const f16x8*)(W1F + cb + kt*512);
      W2r[kt] = *(const f16x8*)(W2F + cb + kt*512);
    }
  }

  float loss_loc=0.f, m_loc=0.f;
  int rnd = 0;

#define POLL() do{                                                         \
    if (t < 4){                                                            \
      while (__hip_atomic_load(flgbase + t*32, __ATOMIC_RELAXED,           \
                               __HIP_MEMORY_SCOPE_AGENT) < rnd)            \
        __builtin_amdgcn_s_sleep(1);                                       \
    }                                                                      \
    __syncthreads();                                                       \
  }while(0)

#define PUBLISH() do{                                                      \
    asm volatile("s_waitcnt vmcnt(0)" ::: "memory");                       \
    __syncthreads();                                                       \
    rnd++;                                                                 \
    if (t == 0)                                                            \
      __hip_atomic_store(flgbase + s*32, rnd, __ATOMIC_RELAXED,            \
                         __HIP_MEMORY_SCOPE_AGENT);                        \
  }while(0)

// stage 16 rows x 512 cols (mirror, row-major) -> frag layout
#define STAGE(DST, SRCPTR) do{                                             \
    const int ar = t & 15, ch = t >> 4;  /* ch 0..31: 16 cols */           \
    const u64* sp = (const u64*)((SRCPTR) + ((size_t)(g*16+ar))*512 + ch*16); \
    u64 v0=ald(sp), v1=ald(sp+1), v2=ald(sp+2), v3=ald(sp+3);              \
    const int kt = ch >> 1, bl = ar + ((ch & 1) << 5);                     \
    u64* d0 = (u64*)((DST) + kt*512 + bl*8);                               \
    d0[0]=v0; d0[1]=v1;                                                    \
    u64* d1 = (u64*)((DST) + kt*512 + (bl+16)*8);                          \
    d1[0]=v2; d1[1]=v3;                                                    \
  }while(0)

  for (int k=0; k<Kn; k++){
    // ========= P1e: [deferred P2 (k-1)] + Euler step1-W1 =========
    POLL();
    if (k > 0) STAGE(Bfrag, T2f);
    {   // stage h: per-row select Hf2 (obs at k-1) else Hf
      const int ar = t & 15, ch = t >> 4;
      const __half* hsrc = (k > 0 && posk[ar] >= 0) ? Hf2 : Hf;
      const u64* sp = (const u64*)(hsrc + ((size_t)(g*16+ar))*512 + ch*16);
      u64 v0=ald(sp), v1=ald(sp+1), v2=ald(sp+2), v3=ald(sp+3);
      const int kt = ch >> 1, bl = ar + ((ch & 1) << 5);
      u64* d0 = (u64*)(Afrag + kt*512 + bl*8);
      d0[0]=v0; d0[1]=v1;
      u64* d1 = (u64*)(Afrag + kt*512 + (bl+16)*8);
      d1[0]=v2; d1[1]=v3;
    }
    __syncthreads();
    {   // W1 matvec, in-lane tanh -> Tf
      f32x4 a1 = mv16r(Afrag, W1r, lane);
      #pragma unroll
      for (int i=0;i<4;i++)
        ash(Tf + ((size_t)(g*16 + lq*4 + i))*512 + colg, tanhf(a1[i] + b1v));
    }
    if (k > 0){   // deferred P2 partial: coltile 2s+(w&1), kt quarter w>>1
      const int ct2 = 2*s + (w&1), kq = w >> 1;
      const __half* wb = Wp2F + ((size_t)ct2*16 + kq*4)*512 + (size_t)lane*8;
      f32x4 p2 = {0,0,0,0};
      #pragma unroll
      for (int kt2=0; kt2<4; kt2++){
        f16x8 a = *(const f16x8*)(Bfrag + (kq*4+kt2)*512 + lane*8);
        f16x8 b = *(const f16x8*)(wb + (size_t)kt2*512);
        p2 = __builtin_amdgcn_mfma_f32_16x16x32_f16(a, b, p2, 0,0,0);
      }
      float* o = outb + ((w&1)*4 + kq)*256 + (lq*4)*16 + li;
      o[0]=p2[0]; o[16]=p2[1]; o[32]=p2[2]; o[48]=p2[3];
    }
    PUBLISH();
    if (k > 0){   // loss (k-1) in barrier shadow; posk still holds k-1
      const int row = t >> 5, c32 = t & 31;
      const int ep = posk[row];
      if (ep >= 0){
        float p = bp2v;
        #pragma unroll
        for (int q=0;q<4;q++)
          p += outb[((c32>>4)*4 + q)*256 + row*16 + (c32&15)];
        const size_t xo = ((size_t)((k-1)*En+ep))*Dn + s*32 + c32;
        float mo = Mm[xo];
        loss_loc += fabsf(X[xo] - p)*mo;
        m_loc    += mo;
      }
    }

    // ========= P2e: Euler step1-W2, h += dt(..) =========
    POLL();
    STAGE(Afrag, Tf);
    __syncthreads();
    {
      f32x4 a2 = mv16r(Afrag, W2r, lane);
      #pragma unroll
      for (int i=0;i<4;i++){
        Hreg[i] += DT_C*(a2[i] + b2v);
        ash(Hf + ((size_t)(g*16 + lq*4 + i))*512 + colg, Hreg[i]);
      }
    }
    PUBLISH();

    // ========= P3e: Euler step2-W1 =========
    POLL();
    STAGE(Afrag, Hf);
    __syncthreads();
    {
      f32x4 a1 = mv16r(Afrag, W1r, lane);
      #pragma unroll
      for (int i=0;i<4;i++)
        ash(Tf + ((size_t)(g*16 + lq*4 + i))*512 + colg, tanhf(a1[i] + b1v));
    }
    PUBLISH();

    // ========= P4e: Euler step2-W2 =========
    POLL();
    STAGE(Afrag, Tf);
    __syncthreads();
    {
      f32x4 a2 = mv16r(Afrag, W2r, lane);
      #pragma unroll
      for (int i=0;i<4;i++){
        Hreg[i] += DT_C*(a2[i] + b2v);
        ash(Hf + ((size_t)(g*16 + lq*4 + i))*512 + colg, Hreg[i]);
      }
    }
    PUBLISH();

    // ========= P56: Wp1->T2f, gates, LSTM->Hf2 =========
    POLL();
    STAGE(Afrag, Hf);
    if (t < 16) posk[t] = pos[(k<<9) + g*16 + t];
    if (t < 128){   // stage X (16 rows x 128 cols, full X row)
      const int ar = t & 15, ch = (t >> 4) & 7;
      const int e = pos[(k<<9) + g*16 + ar];
      float xv[16];
      if (e >= 0){
        const float4* xp = (const float4*)(X + ((size_t)(k*En+e))*Dn + ch*16);
        #pragma unroll
        for (int i2=0;i2<4;i2++){
          float4 f = xp[i2];
          xv[4*i2]=f.x; xv[4*i2+1]=f.y; xv[4*i2+2]=f.z; xv[4*i2+3]=f.w;
        }
      } else {
        #pragma unroll
        for (int i2=0;i2<16;i2++) xv[i2]=0.f;
      }
      const int kt = ch >> 1, bl = ar + ((ch & 1) << 5);
      union { __half h[8]; u64 q[2]; } u0, u1;
      #pragma unroll
      for (int e8=0;e8<8;e8++){ u0.h[e8]=__float2half(xv[e8]); u1.h[e8]=__float2half(xv[8+e8]); }
      u64* d0 = (u64*)(Xfrag + kt*512 + bl*8);
      d0[0]=u0.q[0]; d0[1]=u0.q[1];
      u64* d1 = (u64*)(Xfrag + kt*512 + (bl+16)*8);
      d1[0]=u1.q[0]; d1[1]=u1.q[1];
    }
    __syncthreads();
    {   // Wp1 (streamed), in-lane relu -> T2f
      const __half* wb = Wp1F + (size_t)ctw*16*512 + (size_t)lane*8;
      f32x4 p1 = {0,0,0,0};
      #pragma unroll
      for (int kt=0; kt<16; kt++){
        f16x8 a = *(const f16x8*)(Afrag + kt*512 + lane*8);
        f16x8 b = *(const f16x8*)(wb + (size_t)kt*512);
        p1 = __builtin_amdgcn_mfma_f32_16x16x32_f16(a, b, p1, 0,0,0);
      }
      #pragma unroll
      for (int i=0;i<4;i++)
        ash(T2f + ((size_t)(g*16 + lq*4 + i))*512 + colg, fmaxf(p1[i] + bp1v, 0.f));
    }
    if (k < Kn-1){
      // gates: interleaved layout, in-lane accumulators (4 gates, own coltile)
      const __half* wgb = WgF + ((size_t)(ctw*4)*20)*512 + (size_t)lane*8;
      f32x4 ga[4];
      #pragma unroll
      for (int i=0;i<4;i++) ga[i]=(f32x4){0,0,0,0};
      #pragma unroll
      for (int kt=0; kt<20; kt++){
        f16x8 a = (kt < 4)
          ? *(const f16x8*)(Xfrag + kt*512 + lane*8)
          : *(const f16x8*)(Afrag + (kt-4)*512 + lane*8);
        #pragma unroll
        for (int gg=0; gg<4; gg++){
          f16x8 b = *(const f16x8*)(wgb + (size_t)(gg*20 + kt)*512);
          ga[gg] = __builtin_amdgcn_mfma_f32_16x16x32_f16(a, b, ga[gg], 0,0,0);
        }
      }
      // in-lane LSTM (rows lq*4+i, col colg)
      #pragma unroll
      for (int i=0;i<4;i++){
        const int r = lq*4 + i;
        if (posk[r] >= 0){
          float ig = sigm (ga[0][i] + biv);
          float fg = sigm (ga[1][i] + bfv);
          float og = sigm (ga[2][i] + bov);
          float ct = tanhf(ga[3][i] + bcv);
          Creg[i] = fg*Creg[i] + ig*ct;
          Hreg[i] = og*tanhf(Creg[i]);
          ash(Hf2 + ((size_t)(g*16 + r))*512 + colg, Hreg[i]);
        }
      }
    }
    PUBLISH();
  }

  // ===== epilogue: deferred P2+loss for event Kn-1 =====
  POLL();
  STAGE(Bfrag, T2f);
  __syncthreads();
  {
    const int ct2 = 2*s + (w&1), kq = w >> 1;
    const __half* wb = Wp2F + ((size_t)ct2*16 + kq*4)*512 + (size_t)lane*8;
    f32x4 p2 = {0,0,0,0};
    #pragma unroll
    for (int kt2=0; kt2<4; kt2++){
      f16x8 a = *(const f16x8*)(Bfrag + (kq*4+kt2)*512 + lane*8);
      f16x8 b = *(const f16x8*)(wb + (size_t)kt2*512);
      p2 = __builtin_amdgcn_mfma_f32_16x16x32_f16(a, b, p2, 0,0,0);
    }
    float* o = outb + ((w&1)*4 + kq)*256 + (lq*4)*16 + li;
    o[0]=p2[0]; o[16]=p2[1]; o[32]=p2[2]; o[48]=p2[3];
  }
  __syncthreads();
  {
    const int row = t >> 5, c32 = t & 31;
    const int ep = posk[row];
    if (ep >= 0){
      float p = bp2v;
      #pragma unroll
      for (int q=0;q<4;q++)
        p += outb[((c32>>4)*4 + q)*256 + row*16 + (c32&15)];
      const size_t xo = ((size_t)((Kn-1)*En+ep))*Dn + s*32 + c32;
      float mo = Mm[xo];
      loss_loc += fabsf(X[xo] - p)*mo;
      m_loc    += mo;
    }
  }

  // block reduction -> global atomics
  #pragma unroll
  for (int off=32; off>0; off>>=1){
    loss_loc += __shfl_down(loss_loc, off);
    m_loc    += __shfl_down(m_loc, off);
  }
  if (lane == 0){ redbuf[w] = loss_loc; redbuf[8+w] = m_loc; }
  __syncthreads();
  if (t == 0){
    float L=0.f, Mt=0.f;
    #pragma unroll
    for (int i=0;i<8;i++){ L += redbuf[i]; Mt += redbuf[8+i]; }
    atomicAdd(acc+0, L);
    atomicAdd(acc+1, Mt);
  }
#undef POLL
#undef PUBLISH
#undef STAGE
}

__global__ void k_fin(const float* __restrict__ acc, float* __restrict__ out){
  if (threadIdx.x == 0){
    out[0] = acc[0];
    out[1] = acc[0]/acc[1];
  }
}

extern "C" void kernel_launch(void* const* d_in, const int* in_sizes, int n_in,
                              void* d_out, int out_size, void* d_ws, size_t ws_size,
                              hipStream_t stream)
{
  const float* X   = (const float*)d_in[0];
  const float* Mm  = (const float*)d_in[1];
  const int*  bidx = (const int*)d_in[2];
  // d_in[3] = sample_idx (arange, unused)
  const float* Wi  = (const float*)d_in[4];
  const float* bi  = (const float*)d_in[5];
  const float* Wf  = (const float*)d_in[6];
  const float* bff = (const float*)d_in[7];
  const float* Wo  = (const float*)d_in[8];
  const float* bo  = (const float*)d_in[9];
  const float* Wc  = (const float*)d_in[10];
  const float* bc  = (const float*)d_in[11];
  const float* W1  = (const float*)d_in[12];
  const float* b1  = (const float*)d_in[13];
  const float* W2  = (const float*)d_in[14];
  const float* b2  = (const float*)d_in[15];
  const float* Wp1 = (const float*)d_in[16];
  const float* bp1 = (const float*)d_in[17];
  const float* Wp2 = (const float*)d_in[18];
  const float* bp2 = (const float*)d_in[19];

  char* ws = (char*)d_ws;
  int*    pos = (int*)ws;
  float*  acc = (float*)(ws + 131072);
  int*    flg = (int*)(ws + 196608);
  __half* Hf  = (__half*)(ws + 1048576);
  __half* Tf  = (__half*)(ws + 1572864);
  __half* T2f = (__half*)(ws + 2097152);
  __half* Hf2 = (__half*)(ws + 2621440);
  __half* WF  = (__half*)(ws + 4194304);

  k_init   <<<512, 256, 0, stream>>>(pos, acc, flg, (uint32_t*)Hf);
  k_scatter<<<(Kn*En + 255)/256, 256, 0, stream>>>(bidx, pos);

  k_cvt_frag<<<(262144+255)/256, 256, 0, stream>>>(W1,  WF,          16, 512, 262144);
  k_cvt_frag<<<(262144+255)/256, 256, 0, stream>>>(W2,  WF + 262144, 16, 512, 262144);
  k_cvt_frag<<<(262144+255)/256, 256, 0, stream>>>(Wp1, WF + 524288, 16, 512, 262144);
  k_cvt_frag<<<(65536 +255)/256, 256, 0, stream>>>(Wp2, WF + 786432, 16, 128, 65536);
  k_cvt_gate<<<(327680+255)/256, 256, 0, stream>>>(Wi, WF + 851968, 0);
  k_cvt_gate<<<(327680+255)/256, 256, 0, stream>>>(Wf, WF + 851968, 1);
  k_cvt_gate<<<(327680+255)/256, 256, 0, stream>>>(Wo, WF + 851968, 2);
  k_cvt_gate<<<(327680+255)/256, 256, 0, stream>>>(Wc, WF + 851968, 3);

  k_main<<<NBLK, NTH, 0, stream>>>(X, Mm, pos, WF, Hf, Tf, T2f, Hf2,
                                   bi, bff, bo, bc, b1, b2, bp1, bp2, acc, flg);
  k_fin<<<1, 64, 0, stream>>>(acc, (float*)d_out);
}